// Round 4
// baseline (22104.175 us; speedup 1.0000x reference)
//
#include <hip/hip_runtime.h>
#include <hip/hip_bf16.h>
#include <math.h>

#define N_NODES 50000
#define N_EDGES 1600000
#define N_FEAT  256
#define HIDDEN  32
#define N_CLASS 64
#define NBUCK   391      // ceil(50000 / 128) nodes-per-bucket = 128
#define EPB     7168     // edges per block in bin_edges
#define CAP     6144     // max staged edges per bucket in build_csr (avg 4096)
#define NITEM   12500    // spmm work items: 4 quarters x 3125 node-groups(16 nodes)

// ---------------- CSR build via bucket binning (unchanged from R2) ----------------

__global__ __launch_bounds__(256) void bucket_count(const int* __restrict__ dst,
                                                    int* __restrict__ gcnt) {
  __shared__ int h[NBUCK];
  for (int i = threadIdx.x; i < NBUCK; i += 256) h[i] = 0;
  __syncthreads();
  int base = blockIdx.x * 8192;
  for (int i = threadIdx.x; i < 8192; i += 256) {
    int e = base + i;
    if (e < N_EDGES) atomicAdd(&h[dst[e] >> 7], 1);
  }
  __syncthreads();
  for (int i = threadIdx.x; i < NBUCK; i += 256)
    if (h[i]) atomicAdd(&gcnt[i], h[i]);
}

__global__ __launch_bounds__(512) void bucket_scan(const int* __restrict__ gcnt,
                                                   int* __restrict__ goff) {
  __shared__ int s[512];
  int t = threadIdx.x;
  int v = (t < NBUCK) ? gcnt[t] : 0;
  s[t] = v;
  __syncthreads();
  for (int off = 1; off < 512; off <<= 1) {
    int u = (t >= off) ? s[t - off] : 0;
    __syncthreads();
    s[t] += u;
    __syncthreads();
  }
  if (t <= NBUCK) goff[t] = (t == 0) ? 0 : s[t - 1];
}

__global__ __launch_bounds__(256) void bin_edges(const int* __restrict__ src,
                                                 const int* __restrict__ dst,
                                                 const float* __restrict__ val,
                                                 const int* __restrict__ goff,
                                                 int* __restrict__ bcur,
                                                 int2* __restrict__ st) {
  __shared__ int h[NBUCK];
  __shared__ int lstart[NBUCK];
  __shared__ int lcur[NBUCK];
  __shared__ int gbase[NBUCK];
  __shared__ int2 stage[EPB];
  int t = threadIdx.x;
  for (int i = t; i < NBUCK; i += 256) { h[i] = 0; lcur[i] = 0; }
  __syncthreads();
  int base = blockIdx.x * EPB;
  int nloc = min(EPB, N_EDGES - base);
  for (int i = t; i < nloc; i += 256) atomicAdd(&h[dst[base + i] >> 7], 1);
  __syncthreads();
  if (t < 64) {
    int loc[7];
    int s0 = 0;
#pragma unroll
    for (int i = 0; i < 7; ++i) {
      int b = t * 7 + i;
      int c = (b < NBUCK) ? h[b] : 0;
      loc[i] = s0; s0 += c;
    }
    int run = s0;
#pragma unroll
    for (int off = 1; off < 64; off <<= 1) {
      int u = __shfl_up(run, off);
      if (t >= off) run += u;
    }
    int excl = run - s0;
#pragma unroll
    for (int i = 0; i < 7; ++i) {
      int b = t * 7 + i;
      if (b < NBUCK) lstart[b] = excl + loc[i];
    }
  }
  __syncthreads();
  for (int i = t; i < NBUCK; i += 256) {
    int c = h[i];
    gbase[i] = c ? (goff[i] + atomicAdd(&bcur[i], c)) : 0;
  }
  __syncthreads();
  for (int i = t; i < nloc; i += 256) {
    int e = base + i;
    int d = dst[e];
    int b = d >> 7;
    int pos = lstart[b] + atomicAdd(&lcur[b], 1);
    stage[pos] = make_int2((src[e] << 16) | d, __float_as_int(val[e]));
  }
  __syncthreads();
  for (int i = t; i < nloc; i += 256) {
    int2 v = stage[i];
    int b = (v.x & 0xffff) >> 7;
    st[gbase[b] + (i - lstart[b])] = v;
  }
}

__global__ __launch_bounds__(256) void build_csr(const int* __restrict__ goff,
                                                 const int2* __restrict__ st,
                                                 int* __restrict__ rp,
                                                 int2* __restrict__ ep) {
  __shared__ int2 stage[CAP];
  __shared__ int lh[128], lstart[128], lcur[128];
  int b = blockIdx.x, t = threadIdx.x;
  int beg = goff[b], end = goff[b + 1];
  int n = min(end - beg, CAP);
  for (int i = t; i < 128; i += 256) { lh[i] = 0; lcur[i] = 0; }
  __syncthreads();
  for (int i = t; i < n; i += 256) {
    int2 v = st[beg + i];
    stage[i] = v;
    atomicAdd(&lh[v.x & 127], 1);
  }
  __syncthreads();
  if (t < 64) {
    int a0 = lh[2 * t], a1 = lh[2 * t + 1];
    int s0 = a0 + a1;
    int run = s0;
#pragma unroll
    for (int off = 1; off < 64; off <<= 1) {
      int u = __shfl_up(run, off);
      if (t >= off) run += u;
    }
    int excl = run - s0;
    lstart[2 * t] = excl;
    lstart[2 * t + 1] = excl + a0;
  }
  __syncthreads();
  int nodebase = b * 128;
  int nn = min(128, N_NODES - nodebase);
  for (int i = t; i < nn; i += 256) rp[nodebase + i] = beg + lstart[i];
  if (b == NBUCK - 1 && t == 0) rp[N_NODES] = N_EDGES;
  for (int i = t; i < n; i += 256) {
    int2 v = stage[i];
    int d = v.x & 127;
    int pos = lstart[d] + atomicAdd(&lcur[d], 1);
    ep[beg + pos] = make_int2((int)(((unsigned)v.x) >> 16), v.y);
  }
}

// ---------------- MLP + softmax -> p0 ----------------
// block = 256 thr / 64 nodes; wave w = feat chunk [64w,64w+64).
// x staged coalesced into 64KB XOR-swizzled LDS tile xs[feat][node^feat].

__global__ __launch_bounds__(256) void mlp_kernel(const float* __restrict__ x,
                                                  const float* __restrict__ W1,
                                                  const float* __restrict__ b1,
                                                  const float* __restrict__ W2,
                                                  const float* __restrict__ b2,
                                                  float* __restrict__ P) {
  __shared__ float lds[N_FEAT * 64];   // 64 KB; regions reused after syncs
  float* xs = lds;                     // [256][64] xor-swizzled
  float* hs = lds;                     // [4][64][33] after xs dead
  float* hfull = lds + 8448;           // [64][33]
  float* ps = lds;                     // [64][65] after hs dead

  int t = threadIdx.x;
  int w = __builtin_amdgcn_readfirstlane(t >> 6);
  int l = t & 63;
  int n0 = blockIdx.x * 64;

  // stage x tile: coalesced float4 global reads, xor-swizzled b32 LDS writes
#pragma unroll 4
  for (int pass = 0; pass < 16; ++pass) {
    int idx = pass * 256 + t;      // 0..4095 float4 slots
    int row = idx >> 6;            // node-local 0..63
    int c4 = idx & 63;             // float4 column
    float4 v = make_float4(0.f, 0.f, 0.f, 0.f);
    if (n0 + row < N_NODES)
      v = *(const float4*)(x + (size_t)(n0 + row) * N_FEAT + c4 * 4);
    int f0 = c4 * 4;
    xs[(f0 + 0) * 64 + (row ^ ((f0 + 0) & 63))] = v.x;
    xs[(f0 + 1) * 64 + (row ^ ((f0 + 1) & 63))] = v.y;
    xs[(f0 + 2) * 64 + (row ^ ((f0 + 2) & 63))] = v.z;
    xs[(f0 + 3) * 64 + (row ^ ((f0 + 3) & 63))] = v.w;
  }
  __syncthreads();

  // layer 1 partials: wave w over its 64 feats; W1 rows via scalar loads
  float h[HIDDEN];
#pragma unroll
  for (int j = 0; j < HIDDEN; ++j) h[j] = 0.f;
  for (int k = 0; k < 64; ++k) {
    int kp = w * 64 + k;
    float xk = xs[kp * 64 + (l ^ (kp & 63))];
    const float* wr = W1 + kp * HIDDEN;   // uniform -> s_load
#pragma unroll
    for (int j = 0; j < HIDDEN; ++j) h[j] = fmaf(xk, wr[j], h[j]);
  }
  __syncthreads();   // xs dead
#pragma unroll
  for (int j = 0; j < HIDDEN; ++j) hs[w * 2112 + l * 33 + j] = h[j];
  __syncthreads();

  // reduce partials + bias + ReLU: thread t -> node t>>2, j-range (t&3)*8..+8
  {
    int n = t >> 2, j0 = (t & 3) * 8;
#pragma unroll
    for (int i = 0; i < 8; ++i) {
      int j = j0 + i;
      float v = hs[n * 33 + j] + hs[2112 + n * 33 + j] +
                hs[4224 + n * 33 + j] + hs[6336 + n * 33 + j];
      hfull[n * 33 + j] = fmaxf(v + b1[j], 0.f);
    }
  }
  __syncthreads();

  // layer 2: wave w -> classes [16w,16w+16); lane l = node; W2 scalar loads
  float p[16];
#pragma unroll
  for (int c = 0; c < 16; ++c) p[c] = b2[16 * w + c];
  for (int kk = 0; kk < HIDDEN; ++kk) {
    float hk = hfull[l * 33 + kk];
    const float* w2r = W2 + kk * N_CLASS + 16 * w;  // uniform -> s_load
#pragma unroll
    for (int c = 0; c < 16; ++c) p[c] = fmaf(hk, w2r[c], p[c]);
  }
  __syncthreads();   // hfull readers done before ps (offset 0) overwrite? ps
                     // overlaps hs region only; hfull at 8448 stays intact.
#pragma unroll
  for (int c = 0; c < 16; ++c) ps[l * 65 + 16 * w + c] = p[c];
  __syncthreads();

  // softmax: thread t -> node t>>2, class-chunk (t&3)*16
  {
    int n = t >> 2, ck = (t & 3) * 16;
    float q[16];
    float m = -1e30f;
#pragma unroll
    for (int i = 0; i < 16; ++i) { q[i] = ps[n * 65 + ck + i]; m = fmaxf(m, q[i]); }
    m = fmaxf(m, __shfl_xor(m, 1));
    m = fmaxf(m, __shfl_xor(m, 2));
    float s = 0.f;
#pragma unroll
    for (int i = 0; i < 16; ++i) { q[i] = expf(q[i] - m); s += q[i]; }
    s += __shfl_xor(s, 1);
    s += __shfl_xor(s, 2);
    float inv = 1.f / s;
    int gn = n0 + n;
    if (gn < N_NODES) {
      float4* op = (float4*)(P + (size_t)gn * N_CLASS + ck);
#pragma unroll
      for (int i4 = 0; i4 < 4; ++i4)
        op[i4] = make_float4(q[i4 * 4] * inv, q[i4 * 4 + 1] * inv,
                             q[i4 * 4 + 2] * inv, q[i4 * 4 + 3] * inv);
    }
  }
}

// ---------------- SpMM + 0.5*tanh, channel-quartered, real-XCD affinity ------
// Block claims one item (quarter q, 16-node group) matching its OWN XCD via
// per-quarter cursor; CAS-claim + global fallback keeps correctness under any
// dispatch placement. Each XCD pair gathers only its 3.2MB slice -> L2-resident.

__global__ __launch_bounds__(256) void spmm_q2(const int* __restrict__ rp,
                                               const int2* __restrict__ ep,
                                               const float* __restrict__ pin,
                                               float* __restrict__ pout,
                                               int* __restrict__ cur,
                                               int* __restrict__ claim) {
  __shared__ int s_item;
  int xcc;
  asm volatile("s_getreg_b32 %0, hwreg(20, 0, 4)" : "=s"(xcc));
  if (threadIdx.x == 0) {
    int myq = (xcc >> 1) & 3;
    int item = -1, it;
    while ((it = atomicAdd(&cur[myq], 1)) < 3125) {
      int cand = myq * 3125 + it;
      if (atomicCAS(&claim[cand], 0, 1) == 0) { item = cand; break; }
    }
    if (item < 0) {
      int gg;
      while ((gg = atomicAdd(&cur[4], 1)) < NITEM) {
        if (atomicCAS(&claim[gg], 0, 1) == 0) { item = gg; break; }
      }
    }
    s_item = item;
  }
  __syncthreads();
  int item = s_item;
  if (item < 0) return;
  int q = item / 3125;
  int ng = item - q * 3125;
  int wv = threadIdx.x >> 6, lane = threadIdx.x & 63;
  int c = lane & 15, g4 = lane >> 4;
  const float* pq = pin + q * 16 + c;
  const long long* epl = (const long long*)ep;
  int nb = ng * 16 + wv * 4;
#pragma unroll
  for (int i = 0; i < 4; ++i) {
    int node = nb + i;
    int beg = rp[node], end = rp[node + 1];
    float acc = 0.f;
    for (int base = beg; base < end; base += 64) {
      int idx = base + lane;
      long long raw = (idx < end) ? __builtin_nontemporal_load(epl + idx) : 0LL;
      int ex = (int)raw;
      float ev = __int_as_float((int)(raw >> 32));
      int cnt = min(64, end - base);
#pragma unroll 4
      for (int j = g4; j < cnt; j += 4) {
        int   sj = __shfl(ex, j);
        float vj = __shfl(ev, j);
        acc = fmaf(vj, pq[(size_t)sj << 6], acc);
      }
    }
    acc += __shfl_xor(acc, 16);
    acc += __shfl_xor(acc, 32);
    if (g4 == 0) pout[((size_t)node << 6) + q * 16 + c] = 0.5f * tanhf(acc);
  }
}

// ---------------- final row softmax ----------------

__global__ __launch_bounds__(256) void softmax_kernel(const float* __restrict__ pin,
                                                      float* __restrict__ out) {
  int t = threadIdx.x;
  int node = blockIdx.x * 16 + (t >> 4);
  int c = t & 15;
  float4 v = ((const float4*)(pin + (size_t)node * N_CLASS))[c];
  float m = fmaxf(fmaxf(v.x, v.y), fmaxf(v.z, v.w));
#pragma unroll
  for (int off = 1; off <= 8; off <<= 1) m = fmaxf(m, __shfl_xor(m, off));
  float4 e;
  e.x = expf(v.x - m); e.y = expf(v.y - m);
  e.z = expf(v.z - m); e.w = expf(v.w - m);
  float s = e.x + e.y + e.z + e.w;
#pragma unroll
  for (int off = 1; off <= 8; off <<= 1) s += __shfl_xor(s, off);
  float inv = 1.f / s;
  ((float4*)(out + (size_t)node * N_CLASS))[c] =
      make_float4(e.x * inv, e.y * inv, e.z * inv, e.w * inv);
}

// ---------------- launch ----------------

extern "C" void kernel_launch(void* const* d_in, const int* in_sizes, int n_in,
                              void* d_out, int out_size, void* d_ws, size_t ws_size,
                              hipStream_t stream) {
  const float* x    = (const float*)d_in[0];
  const int*   esrc = (const int*)d_in[1];
  const int*   edst = (const int*)d_in[2];
  const float* evl  = (const float*)d_in[3];
  const float* W1   = (const float*)d_in[4];
  const float* b1   = (const float*)d_in[5];
  const float* W2   = (const float*)d_in[6];
  const float* b2   = (const float*)d_in[7];
  float* out = (float*)d_out;

  char* ws = (char*)d_ws;
  float* Pa    = (float*)(ws);                      // 12.8 MB (aliases st)
  float* Pb    = (float*)(ws + 12800000);           // 12.8 MB
  int2*  ep    = (int2*) (ws + 25600000);           // 12.8 MB
  int2*  st    = (int2*) (ws);                      // dead before mlp writes Pa
  int*   gcnt  = (int*)(ws + 38400000);             // 400 ints
  int*   bcur  = (int*)(ws + 38401600);             // 400 ints
  int*   curs  = (int*)(ws + 38403200);             // 4 dispatches x 8 ints
  int*   claim = (int*)(ws + 38403328);             // 4 x 12500 ints
  int*   goff  = (int*)(ws + 38603328);             // 400 ints
  int*   rp    = (int*)(ws + 38604928);             // 50001 ints

  // zero gcnt+bcur+cursors+claims in one shot (203,328 B)
  hipMemsetAsync(gcnt, 0, 203328, stream);

  bucket_count<<<196, 256, 0, stream>>>(edst, gcnt);
  bucket_scan<<<1, 512, 0, stream>>>(gcnt, goff);
  bin_edges<<<224, 256, 0, stream>>>(esrc, edst, evl, goff, bcur, st);
  build_csr<<<NBUCK, 256, 0, stream>>>(goff, st, rp, ep);

  mlp_kernel<<<782, 256, 0, stream>>>(x, W1, b1, W2, b2, Pa);

  spmm_q2<<<NITEM, 256, 0, stream>>>(rp, ep, Pa, Pb, curs + 0,  claim + 0);
  spmm_q2<<<NITEM, 256, 0, stream>>>(rp, ep, Pb, Pa, curs + 8,  claim + 12500);
  spmm_q2<<<NITEM, 256, 0, stream>>>(rp, ep, Pa, Pb, curs + 16, claim + 25000);
  spmm_q2<<<NITEM, 256, 0, stream>>>(rp, ep, Pb, Pa, curs + 24, claim + 37500);

  softmax_kernel<<<3125, 256, 0, stream>>>(Pa, out);
}

// Round 5
// 2913.589 us; speedup vs baseline: 7.5866x; 7.5866x over previous
//
#include <hip/hip_runtime.h>
#include <hip/hip_bf16.h>
#include <math.h>

#define N_NODES 50000
#define N_EDGES 1600000
#define N_FEAT  256
#define HIDDEN  32
#define N_CLASS 64
#define NBUCK   782      // ceil(50000 / 64): 64 dst nodes per bucket
#define NBPL    13       // bins per lane in bin_edges wave scan (64*13 >= 782)
#define EPB     6144     // edges per block in bin_edges (LDS fit: 48KB stage + 12.5KB bins)
#define CAP2    3072     // max edges per bucket in resort (mean 2048, Poisson sigma ~45)

// ---------------- stage 1: per-bucket edge counts ----------------

__global__ __launch_bounds__(256) void bucket_count(const int* __restrict__ dst,
                                                    int* __restrict__ gcnt) {
  __shared__ int h[NBUCK];
  for (int i = threadIdx.x; i < NBUCK; i += 256) h[i] = 0;
  __syncthreads();
  int base = blockIdx.x * 8192;
  for (int i = threadIdx.x; i < 8192; i += 256) {
    int e = base + i;
    if (e < N_EDGES) atomicAdd(&h[dst[e] >> 6], 1);
  }
  __syncthreads();
  for (int i = threadIdx.x; i < NBUCK; i += 256)
    if (h[i]) atomicAdd(&gcnt[i], h[i]);
}

// ---------------- stage 2: exclusive scan of 782 bucket counts ----------------

__global__ __launch_bounds__(1024) void bucket_scan(const int* __restrict__ gcnt,
                                                    int* __restrict__ goff) {
  __shared__ int s[1024];
  int t = threadIdx.x;
  int v = (t < NBUCK) ? gcnt[t] : 0;
  s[t] = v;
  __syncthreads();
  for (int off = 1; off < 1024; off <<= 1) {
    int u = (t >= off) ? s[t - off] : 0;
    __syncthreads();
    s[t] += u;
    __syncthreads();
  }
  if (t <= NBUCK) goff[t] = (t == 0) ? 0 : s[t - 1];
}

// ---------------- stage 3: bin edges into bucket-contiguous staging ----------
// stage entry: x = (dst<<16)|src  (both < 65536), y = val bits.

__global__ __launch_bounds__(256) void bin_edges(const int* __restrict__ src,
                                                 const int* __restrict__ dst,
                                                 const float* __restrict__ val,
                                                 const int* __restrict__ goff,
                                                 int* __restrict__ bcur,
                                                 int2* __restrict__ st) {
  __shared__ int h[NBUCK];
  __shared__ int lstart[NBUCK];
  __shared__ int lcur[NBUCK];
  __shared__ int gbase[NBUCK];
  __shared__ int2 stage[EPB];   // 48 KB
  int t = threadIdx.x;
  for (int i = t; i < NBUCK; i += 256) { h[i] = 0; lcur[i] = 0; }
  __syncthreads();
  int base = blockIdx.x * EPB;
  int nloc = min(EPB, N_EDGES - base);
  for (int i = t; i < nloc; i += 256) atomicAdd(&h[dst[base + i] >> 6], 1);
  __syncthreads();
  // exclusive scan of h[782]: wave 0, NBPL bins per lane
  if (t < 64) {
    int loc[NBPL];
    int s0 = 0;
#pragma unroll
    for (int i = 0; i < NBPL; ++i) {
      int b = t * NBPL + i;
      int c = (b < NBUCK) ? h[b] : 0;
      loc[i] = s0; s0 += c;
    }
    int run = s0;
#pragma unroll
    for (int off = 1; off < 64; off <<= 1) {
      int u = __shfl_up(run, off);
      if (t >= off) run += u;
    }
    int excl = run - s0;
#pragma unroll
    for (int i = 0; i < NBPL; ++i) {
      int b = t * NBPL + i;
      if (b < NBUCK) lstart[b] = excl + loc[i];
    }
  }
  __syncthreads();
  for (int i = t; i < NBUCK; i += 256) {
    int c = h[i];
    gbase[i] = c ? (goff[i] + atomicAdd(&bcur[i], c)) : 0;
  }
  __syncthreads();
  for (int i = t; i < nloc; i += 256) {
    int e = base + i;
    int d = dst[e];
    int b = d >> 6;
    int pos = lstart[b] + atomicAdd(&lcur[b], 1);
    stage[pos] = make_int2((d << 16) | src[e], __float_as_int(val[e]));
  }
  __syncthreads();
  for (int i = t; i < nloc; i += 256) {
    int2 v = stage[i];
    int b = (int)(((unsigned)v.x) >> 22);   // dst>>6
    st[gbase[b] + (i - lstart[b])] = v;
  }
}

// ---------------- stage 4: per-bucket resort by src>>9 (window locality) -----
// output entry: x = (dloc<<16)|src with dloc = dst&63.

__global__ __launch_bounds__(256) void resort_bucket(const int* __restrict__ goff,
                                                     const int2* __restrict__ st,
                                                     int2* __restrict__ ep2) {
  __shared__ int2 stage[CAP2];          // 24 KB
  __shared__ int lh[98], lstart[98], lcur[98];
  int b = blockIdx.x, t = threadIdx.x;
  int beg = goff[b], end = goff[b + 1];
  int n = min(end - beg, CAP2);
  for (int i = t; i < 98; i += 256) { lh[i] = 0; lcur[i] = 0; }
  __syncthreads();
  for (int i = t; i < n; i += 256) {
    int2 v = st[beg + i];
    stage[i] = v;
    atomicAdd(&lh[(v.x & 0xffff) >> 9], 1);
  }
  __syncthreads();
  if (t < 64) {
    int i0 = 2 * t, i1 = 2 * t + 1;
    int a0 = (i0 < 98) ? lh[i0] : 0;
    int a1 = (i1 < 98) ? lh[i1] : 0;
    int s0 = a0 + a1;
    int run = s0;
#pragma unroll
    for (int off = 1; off < 64; off <<= 1) {
      int u = __shfl_up(run, off);
      if (t >= off) run += u;
    }
    int excl = run - s0;
    if (i0 < 98) lstart[i0] = excl;
    if (i1 < 98) lstart[i1] = excl + a0;
  }
  __syncthreads();
  for (int i = t; i < n; i += 256) {
    int2 v = stage[i];
    int srcv = v.x & 0xffff;
    int bin = srcv >> 9;
    int dloc = (int)((((unsigned)v.x) >> 16) & 63);
    int pos = lstart[bin] + atomicAdd(&lcur[bin], 1);
    ep2[beg + pos] = make_int2((dloc << 16) | srcv, v.y);
  }
}

// ---------------- MLP + softmax -> p0 (unchanged from R4) ----------------

__global__ __launch_bounds__(256) void mlp_kernel(const float* __restrict__ x,
                                                  const float* __restrict__ W1,
                                                  const float* __restrict__ b1,
                                                  const float* __restrict__ W2,
                                                  const float* __restrict__ b2,
                                                  float* __restrict__ P) {
  __shared__ float lds[N_FEAT * 64];   // 64 KB; regions reused after syncs
  float* xs = lds;                     // [256][64] xor-swizzled
  float* hs = lds;                     // [4][64][33] after xs dead
  float* hfull = lds + 8448;           // [64][33]
  float* ps = lds;                     // [64][65] after hs dead

  int t = threadIdx.x;
  int w = __builtin_amdgcn_readfirstlane(t >> 6);
  int l = t & 63;
  int n0 = blockIdx.x * 64;

#pragma unroll 4
  for (int pass = 0; pass < 16; ++pass) {
    int idx = pass * 256 + t;
    int row = idx >> 6;
    int c4 = idx & 63;
    float4 v = make_float4(0.f, 0.f, 0.f, 0.f);
    if (n0 + row < N_NODES)
      v = *(const float4*)(x + (size_t)(n0 + row) * N_FEAT + c4 * 4);
    int f0 = c4 * 4;
    xs[(f0 + 0) * 64 + (row ^ ((f0 + 0) & 63))] = v.x;
    xs[(f0 + 1) * 64 + (row ^ ((f0 + 1) & 63))] = v.y;
    xs[(f0 + 2) * 64 + (row ^ ((f0 + 2) & 63))] = v.z;
    xs[(f0 + 3) * 64 + (row ^ ((f0 + 3) & 63))] = v.w;
  }
  __syncthreads();

  float h[HIDDEN];
#pragma unroll
  for (int j = 0; j < HIDDEN; ++j) h[j] = 0.f;
  for (int k = 0; k < 64; ++k) {
    int kp = w * 64 + k;
    float xk = xs[kp * 64 + (l ^ (kp & 63))];
    const float* wr = W1 + kp * HIDDEN;   // uniform -> s_load
#pragma unroll
    for (int j = 0; j < HIDDEN; ++j) h[j] = fmaf(xk, wr[j], h[j]);
  }
  __syncthreads();
#pragma unroll
  for (int j = 0; j < HIDDEN; ++j) hs[w * 2112 + l * 33 + j] = h[j];
  __syncthreads();

  {
    int n = t >> 2, j0 = (t & 3) * 8;
#pragma unroll
    for (int i = 0; i < 8; ++i) {
      int j = j0 + i;
      float v = hs[n * 33 + j] + hs[2112 + n * 33 + j] +
                hs[4224 + n * 33 + j] + hs[6336 + n * 33 + j];
      hfull[n * 33 + j] = fmaxf(v + b1[j], 0.f);
    }
  }
  __syncthreads();

  float p[16];
#pragma unroll
  for (int c = 0; c < 16; ++c) p[c] = b2[16 * w + c];
  for (int kk = 0; kk < HIDDEN; ++kk) {
    float hk = hfull[l * 33 + kk];
    const float* w2r = W2 + kk * N_CLASS + 16 * w;  // uniform -> s_load
#pragma unroll
    for (int c = 0; c < 16; ++c) p[c] = fmaf(hk, w2r[c], p[c]);
  }
  __syncthreads();
#pragma unroll
  for (int c = 0; c < 16; ++c) ps[l * 65 + 16 * w + c] = p[c];
  __syncthreads();

  {
    int n = t >> 2, ck = (t & 3) * 16;
    float q[16];
    float m = -1e30f;
#pragma unroll
    for (int i = 0; i < 16; ++i) { q[i] = ps[n * 65 + ck + i]; m = fmaxf(m, q[i]); }
    m = fmaxf(m, __shfl_xor(m, 1));
    m = fmaxf(m, __shfl_xor(m, 2));
    float s = 0.f;
#pragma unroll
    for (int i = 0; i < 16; ++i) { q[i] = expf(q[i] - m); s += q[i]; }
    s += __shfl_xor(s, 1);
    s += __shfl_xor(s, 2);
    float inv = 1.f / s;
    int gn = n0 + n;
    if (gn < N_NODES) {
      float4* op = (float4*)(P + (size_t)gn * N_CLASS + ck);
#pragma unroll
      for (int i4 = 0; i4 < 4; ++i4)
        op[i4] = make_float4(q[i4 * 4] * inv, q[i4 * 4 + 1] * inv,
                             q[i4 * 4 + 2] * inv, q[i4 * 4 + 3] * inv);
    }
  }
}

// ---------------- SpMM + 0.5*tanh: push-based, LDS accumulator ----------------
// One block per 64-dst bucket; acc[64][64] f32 = 16KB LDS; zero global atomics.
// Per edge: wave-wide 256B coalesced row gather + one ds_add_f32 per lane.

__global__ __launch_bounds__(256) void spmm_push(const int* __restrict__ goff,
                                                 const int2* __restrict__ ep2,
                                                 const float* __restrict__ pin,
                                                 float* __restrict__ pout) {
  __shared__ float acc[64 * 64];   // 16 KB
  int b = blockIdx.x, t = threadIdx.x;
  for (int i = t; i < 4096; i += 256) acc[i] = 0.f;
  __syncthreads();
  int beg = goff[b], end = goff[b + 1];
  int w = t >> 6, lane = t & 63;
  const long long* epl = (const long long*)ep2;

  int i = beg + w;
  long long e0 = 0; float r0 = 0.f;
  if (i < end) {
    e0 = __builtin_nontemporal_load(epl + i);
    r0 = pin[((size_t)((int)e0 & 0xffff) << 6) + lane];
  }
  while (i < end) {
    int in = i + 4;
    long long e1 = 0; float r1 = 0.f;
    if (in < end) {
      e1 = __builtin_nontemporal_load(epl + in);
      r1 = pin[((size_t)((int)e1 & 0xffff) << 6) + lane];
    }
    int dloc = ((int)e0 >> 16) & 63;
    float v = __int_as_float((int)(e0 >> 32));
    (void)__hip_atomic_fetch_add(&acc[(dloc << 6) + lane], v * r0,
                                 __ATOMIC_RELAXED, __HIP_MEMORY_SCOPE_WORKGROUP);
    i = in; e0 = e1; r0 = r1;
  }
  __syncthreads();
  int base = b * 64;
  for (int idx = t; idx < 4096; idx += 256) {
    int node = base + (idx >> 6);
    if (node < N_NODES)
      pout[((size_t)node << 6) + (idx & 63)] = 0.5f * tanhf(acc[idx]);
  }
}

// ---------------- final row softmax ----------------

__global__ __launch_bounds__(256) void softmax_kernel(const float* __restrict__ pin,
                                                      float* __restrict__ out) {
  int t = threadIdx.x;
  int node = blockIdx.x * 16 + (t >> 4);
  int c = t & 15;
  float4 v = ((const float4*)(pin + (size_t)node * N_CLASS))[c];
  float m = fmaxf(fmaxf(v.x, v.y), fmaxf(v.z, v.w));
#pragma unroll
  for (int off = 1; off <= 8; off <<= 1) m = fmaxf(m, __shfl_xor(m, off));
  float4 e;
  e.x = expf(v.x - m); e.y = expf(v.y - m);
  e.z = expf(v.z - m); e.w = expf(v.w - m);
  float s = e.x + e.y + e.z + e.w;
#pragma unroll
  for (int off = 1; off <= 8; off <<= 1) s += __shfl_xor(s, off);
  float inv = 1.f / s;
  ((float4*)(out + (size_t)node * N_CLASS))[c] =
      make_float4(e.x * inv, e.y * inv, e.z * inv, e.w * inv);
}

// ---------------- launch ----------------

extern "C" void kernel_launch(void* const* d_in, const int* in_sizes, int n_in,
                              void* d_out, int out_size, void* d_ws, size_t ws_size,
                              hipStream_t stream) {
  const float* x    = (const float*)d_in[0];
  const int*   esrc = (const int*)d_in[1];
  const int*   edst = (const int*)d_in[2];
  const float* evl  = (const float*)d_in[3];
  const float* W1   = (const float*)d_in[4];
  const float* b1   = (const float*)d_in[5];
  const float* W2   = (const float*)d_in[6];
  const float* b2   = (const float*)d_in[7];
  float* out = (float*)d_out;

  char* ws = (char*)d_ws;
  float* Pa   = (float*)(ws);                       // 12.8 MB (aliases st)
  float* Pb   = (float*)(ws + 12800000);            // 12.8 MB
  int2*  ep2  = (int2*) (ws + 25600000);            // 12.8 MB
  int2*  st   = (int2*) (ws);                       // staging, dead before mlp writes Pa
  int*   gcnt = (int*)(ws + 38400000);              // 782 ints
  int*   bcur = (int*)(ws + 38403200);              // 782 ints
  int*   goff = (int*)(ws + 38406400);              // 783 ints

  hipMemsetAsync(gcnt, 0, 6400, stream);  // gcnt + bcur

  bucket_count<<<196, 256, 0, stream>>>(edst, gcnt);
  bucket_scan<<<1, 1024, 0, stream>>>(gcnt, goff);
  bin_edges<<<261, 256, 0, stream>>>(esrc, edst, evl, goff, bcur, st);
  resort_bucket<<<NBUCK, 256, 0, stream>>>(goff, st, ep2);

  mlp_kernel<<<782, 256, 0, stream>>>(x, W1, b1, W2, b2, Pa);

  spmm_push<<<NBUCK, 256, 0, stream>>>(goff, ep2, Pa, Pb);
  spmm_push<<<NBUCK, 256, 0, stream>>>(goff, ep2, Pb, Pa);
  spmm_push<<<NBUCK, 256, 0, stream>>>(goff, ep2, Pa, Pb);
  spmm_push<<<NBUCK, 256, 0, stream>>>(goff, ep2, Pb, Pa);

  softmax_kernel<<<3125, 256, 0, stream>>>(Pa, out);
}

// Round 6
// 343.404 us; speedup vs baseline: 64.3678x; 8.4844x over previous
//
#include <hip/hip_runtime.h>
#include <hip/hip_bf16.h>
#include <math.h>

#define N_NODES 50000
#define N_EDGES 1600000
#define N_FEAT  256
#define HIDDEN  32
#define N_CLASS 64
#define NBUCK   391      // ceil(50000 / 128) nodes-per-bucket = 128
#define EPB     7168     // edges per block in bin_edges
#define CAP     6144     // max staged edges per bucket in build_csr (avg 4096)

typedef _Float16 half_t;
typedef _Float16 half4 __attribute__((ext_vector_type(4)));
typedef _Float16 half8 __attribute__((ext_vector_type(8)));

// ---------------- CSR build via bucket binning (R2-proven) ----------------

__global__ __launch_bounds__(256) void bucket_count(const int* __restrict__ dst,
                                                    int* __restrict__ gcnt) {
  __shared__ int h[NBUCK];
  for (int i = threadIdx.x; i < NBUCK; i += 256) h[i] = 0;
  __syncthreads();
  int base = blockIdx.x * 8192;
  for (int i = threadIdx.x; i < 8192; i += 256) {
    int e = base + i;
    if (e < N_EDGES) atomicAdd(&h[dst[e] >> 7], 1);
  }
  __syncthreads();
  for (int i = threadIdx.x; i < NBUCK; i += 256)
    if (h[i]) atomicAdd(&gcnt[i], h[i]);
}

__global__ __launch_bounds__(512) void bucket_scan(const int* __restrict__ gcnt,
                                                   int* __restrict__ goff) {
  __shared__ int s[512];
  int t = threadIdx.x;
  int v = (t < NBUCK) ? gcnt[t] : 0;
  s[t] = v;
  __syncthreads();
  for (int off = 1; off < 512; off <<= 1) {
    int u = (t >= off) ? s[t - off] : 0;
    __syncthreads();
    s[t] += u;
    __syncthreads();
  }
  if (t <= NBUCK) goff[t] = (t == 0) ? 0 : s[t - 1];
}

__global__ __launch_bounds__(256) void bin_edges(const int* __restrict__ src,
                                                 const int* __restrict__ dst,
                                                 const float* __restrict__ val,
                                                 const int* __restrict__ goff,
                                                 int* __restrict__ bcur,
                                                 int2* __restrict__ st) {
  __shared__ int h[NBUCK];
  __shared__ int lstart[NBUCK];
  __shared__ int lcur[NBUCK];
  __shared__ int gbase[NBUCK];
  __shared__ int2 stage[EPB];   // 56 KB
  int t = threadIdx.x;
  for (int i = t; i < NBUCK; i += 256) { h[i] = 0; lcur[i] = 0; }
  __syncthreads();
  int base = blockIdx.x * EPB;
  int nloc = min(EPB, N_EDGES - base);
  for (int i = t; i < nloc; i += 256) atomicAdd(&h[dst[base + i] >> 7], 1);
  __syncthreads();
  if (t < 64) {
    int loc[7];
    int s0 = 0;
#pragma unroll
    for (int i = 0; i < 7; ++i) {
      int b = t * 7 + i;
      int c = (b < NBUCK) ? h[b] : 0;
      loc[i] = s0; s0 += c;
    }
    int run = s0;
#pragma unroll
    for (int off = 1; off < 64; off <<= 1) {
      int u = __shfl_up(run, off);
      if (t >= off) run += u;
    }
    int excl = run - s0;
#pragma unroll
    for (int i = 0; i < 7; ++i) {
      int b = t * 7 + i;
      if (b < NBUCK) lstart[b] = excl + loc[i];
    }
  }
  __syncthreads();
  for (int i = t; i < NBUCK; i += 256) {
    int c = h[i];
    gbase[i] = c ? (goff[i] + atomicAdd(&bcur[i], c)) : 0;
  }
  __syncthreads();
  for (int i = t; i < nloc; i += 256) {
    int e = base + i;
    int d = dst[e];
    int b = d >> 7;
    int pos = lstart[b] + atomicAdd(&lcur[b], 1);
    stage[pos] = make_int2((src[e] << 16) | d, __float_as_int(val[e]));
  }
  __syncthreads();
  for (int i = t; i < nloc; i += 256) {
    int2 v = stage[i];
    int b = (v.x & 0xffff) >> 7;
    st[gbase[b] + (i - lstart[b])] = v;
  }
}

__global__ __launch_bounds__(256) void build_csr(const int* __restrict__ goff,
                                                 const int2* __restrict__ st,
                                                 int* __restrict__ rp,
                                                 int2* __restrict__ ep) {
  __shared__ int2 stage[CAP];   // 48 KB
  __shared__ int lh[128], lstart[128], lcur[128];
  int b = blockIdx.x, t = threadIdx.x;
  int beg = goff[b], end = goff[b + 1];
  int n = min(end - beg, CAP);
  for (int i = t; i < 128; i += 256) { lh[i] = 0; lcur[i] = 0; }
  __syncthreads();
  for (int i = t; i < n; i += 256) {
    int2 v = st[beg + i];
    stage[i] = v;
    atomicAdd(&lh[v.x & 127], 1);
  }
  __syncthreads();
  if (t < 64) {
    int a0 = lh[2 * t], a1 = lh[2 * t + 1];
    int s0 = a0 + a1;
    int run = s0;
#pragma unroll
    for (int off = 1; off < 64; off <<= 1) {
      int u = __shfl_up(run, off);
      if (t >= off) run += u;
    }
    int excl = run - s0;
    lstart[2 * t] = excl;
    lstart[2 * t + 1] = excl + a0;
  }
  __syncthreads();
  int nodebase = b * 128;
  int nn = min(128, N_NODES - nodebase);
  for (int i = t; i < nn; i += 256) rp[nodebase + i] = beg + lstart[i];
  if (b == NBUCK - 1 && t == 0) rp[N_NODES] = N_EDGES;
  for (int i = t; i < n; i += 256) {
    int2 v = stage[i];
    int d = v.x & 127;
    int pos = lstart[d] + atomicAdd(&lcur[d], 1);
    ep[beg + pos] = make_int2((int)(((unsigned)v.x) >> 16), v.y);
  }
}

// ---------------- MLP + softmax -> p0 (fp16 out) ----------------
// 512 thr / 64 nodes / block; wave w = 32-feat chunk; lane = node.
// LDS: xs[256][64] swizzled (64KB) -> hs[8][64][33] (67.6KB, aliased)
//      + hfull[64][33] @16896; ps[64][65] aliased at 0.

__global__ __launch_bounds__(512) void mlp_kernel(const float* __restrict__ x,
                                                  const float* __restrict__ W1,
                                                  const float* __restrict__ b1,
                                                  const float* __restrict__ W2,
                                                  const float* __restrict__ b2,
                                                  half_t* __restrict__ P) {
  __shared__ float lds[19008];   // 76,032 B -> 2 blocks/CU
  float* xs = lds;
  float* hs = lds;
  float* hfull = lds + 16896;
  float* ps = lds;

  int t = threadIdx.x;
  int w = __builtin_amdgcn_readfirstlane(t >> 6);   // 0..7, wave-uniform
  int l = t & 63;
  int n0 = blockIdx.x * 64;

  // stage x tile: coalesced float4 reads, xor-swizzled LDS writes
#pragma unroll
  for (int pass = 0; pass < 8; ++pass) {
    int idx = pass * 512 + t;     // 0..4095 float4 slots
    int row = idx >> 6;           // node-local
    int c4 = idx & 63;
    float4 v = make_float4(0.f, 0.f, 0.f, 0.f);
    if (n0 + row < N_NODES)
      v = *(const float4*)(x + (size_t)(n0 + row) * N_FEAT + c4 * 4);
    int f0 = c4 * 4;
    xs[(f0 + 0) * 64 + (row ^ ((f0 + 0) & 63))] = v.x;
    xs[(f0 + 1) * 64 + (row ^ ((f0 + 1) & 63))] = v.y;
    xs[(f0 + 2) * 64 + (row ^ ((f0 + 2) & 63))] = v.z;
    xs[(f0 + 3) * 64 + (row ^ ((f0 + 3) & 63))] = v.w;
  }
  __syncthreads();

  // layer 1 partials over this wave's 32 feats; W1 rows via scalar loads
  float h[HIDDEN];
#pragma unroll
  for (int j = 0; j < HIDDEN; ++j) h[j] = 0.f;
#pragma unroll 8
  for (int k = 0; k < 32; ++k) {
    int kp = w * 32 + k;
    float xk = xs[kp * 64 + (l ^ (kp & 63))];
    const float* wr = W1 + kp * HIDDEN;   // uniform -> s_load
#pragma unroll
    for (int j = 0; j < HIDDEN; ++j) h[j] = fmaf(xk, wr[j], h[j]);
  }
  __syncthreads();   // xs dead
#pragma unroll
  for (int j = 0; j < HIDDEN; ++j) hs[w * 2112 + l * 33 + j] = h[j];
  __syncthreads();

  // reduce 8 partials + bias + ReLU: thread t -> node t>>3, j-range (t&7)*4..+4
  {
    int n = t >> 3, j0 = (t & 7) * 4;
#pragma unroll
    for (int i = 0; i < 4; ++i) {
      int j = j0 + i;
      float v = 0.f;
#pragma unroll
      for (int ww = 0; ww < 8; ++ww) v += hs[ww * 2112 + n * 33 + j];
      hfull[n * 33 + j] = fmaxf(v + b1[j], 0.f);
    }
  }
  __syncthreads();

  // layer 2: wave w -> classes [8w, 8w+8); lane l = node
  float p[8];
#pragma unroll
  for (int c = 0; c < 8; ++c) p[c] = b2[8 * w + c];
#pragma unroll 4
  for (int kk = 0; kk < HIDDEN; ++kk) {
    float hk = hfull[l * 33 + kk];
    const float* w2r = W2 + kk * N_CLASS + 8 * w;  // uniform -> s_load
#pragma unroll
    for (int c = 0; c < 8; ++c) p[c] = fmaf(hk, w2r[c], p[c]);
  }
  __syncthreads();   // hs readers (reduce) long done; ps may overwrite [0,4160)
#pragma unroll
  for (int c = 0; c < 8; ++c) ps[l * 65 + 8 * w + c] = p[c];
  __syncthreads();

  // softmax: thread t -> node t>>3, class-chunk (t&7)*8; write fp16
  {
    int n = t >> 3, ck = (t & 7) * 8;
    float q[8];
    float m = -1e30f;
#pragma unroll
    for (int i = 0; i < 8; ++i) { q[i] = ps[n * 65 + ck + i]; m = fmaxf(m, q[i]); }
    m = fmaxf(m, __shfl_xor(m, 1));
    m = fmaxf(m, __shfl_xor(m, 2));
    m = fmaxf(m, __shfl_xor(m, 4));
    float s = 0.f;
#pragma unroll
    for (int i = 0; i < 8; ++i) { q[i] = expf(q[i] - m); s += q[i]; }
    s += __shfl_xor(s, 1);
    s += __shfl_xor(s, 2);
    s += __shfl_xor(s, 4);
    float inv = 1.f / s;
    int gn = n0 + n;
    if (gn < N_NODES) {
      half8 o;
#pragma unroll
      for (int i = 0; i < 8; ++i) o[i] = (half_t)(q[i] * inv);
      *(half8*)(P + (size_t)gn * N_CLASS + ck) = o;
    }
  }
}

// ---------------- SpMM + 0.5*tanh (+ fused final softmax) ----------------
// wave per dst node; 4 edge subgroups x 16 channel-quads; fp16 row gathers
// ((float)half * float fuses to v_fma_mix_f32).

template <int FINAL>
__global__ __launch_bounds__(256) void spmm_kernel(const int* __restrict__ rp,
                                                   const int2* __restrict__ ep,
                                                   const half_t* __restrict__ pin,
                                                   void* __restrict__ pout_) {
  int node = blockIdx.x * 4 + (threadIdx.x >> 6);
  int lane = threadIdx.x & 63;
  int g = lane >> 4;     // edge subgroup 0..3
  int q = lane & 15;     // channel quad: channels 4q..4q+3
  int beg = rp[node], end = rp[node + 1];
  float4 acc = make_float4(0.f, 0.f, 0.f, 0.f);
  for (int base = beg; base < end; base += 64) {
    int idx = base + lane;
    int2 epk = (idx < end) ? ep[idx] : make_int2(0, 0);
    int cnt = min(64, end - base);
#pragma unroll 4
    for (int j = g; j < cnt; j += 4) {
      int   sj = __shfl(epk.x, j);
      float vj = __int_as_float(__shfl(epk.y, j));
      half4 hv = *(const half4*)(pin + ((size_t)sj << 6) + (q << 2));
      acc.x = fmaf(vj, (float)hv[0], acc.x);
      acc.y = fmaf(vj, (float)hv[1], acc.y);
      acc.z = fmaf(vj, (float)hv[2], acc.z);
      acc.w = fmaf(vj, (float)hv[3], acc.w);
    }
  }
#pragma unroll
  for (int off = 16; off <= 32; off <<= 1) {
    acc.x += __shfl_xor(acc.x, off);
    acc.y += __shfl_xor(acc.y, off);
    acc.z += __shfl_xor(acc.z, off);
    acc.w += __shfl_xor(acc.w, off);
  }
  float4 r;
  r.x = 0.5f * tanhf(acc.x);
  r.y = 0.5f * tanhf(acc.y);
  r.z = 0.5f * tanhf(acc.z);
  r.w = 0.5f * tanhf(acc.w);
  if (FINAL) {
    float m = fmaxf(fmaxf(r.x, r.y), fmaxf(r.z, r.w));
#pragma unroll
    for (int off = 1; off <= 8; off <<= 1) m = fmaxf(m, __shfl_xor(m, off));
    float4 e;
    e.x = expf(r.x - m); e.y = expf(r.y - m);
    e.z = expf(r.z - m); e.w = expf(r.w - m);
    float s = e.x + e.y + e.z + e.w;
#pragma unroll
    for (int off = 1; off <= 8; off <<= 1) s += __shfl_xor(s, off);
    float inv = 1.f / s;
    if (g == 0)
      *(float4*)((float*)pout_ + ((size_t)node << 6) + (q << 2)) =
          make_float4(e.x * inv, e.y * inv, e.z * inv, e.w * inv);
  } else {
    if (g == 0) {
      half4 o;
      o[0] = (half_t)r.x; o[1] = (half_t)r.y;
      o[2] = (half_t)r.z; o[3] = (half_t)r.w;
      *(half4*)((half_t*)pout_ + ((size_t)node << 6) + (q << 2)) = o;
    }
  }
}

// ---------------- launch ----------------

extern "C" void kernel_launch(void* const* d_in, const int* in_sizes, int n_in,
                              void* d_out, int out_size, void* d_ws, size_t ws_size,
                              hipStream_t stream) {
  const float* x    = (const float*)d_in[0];
  const int*   esrc = (const int*)d_in[1];
  const int*   edst = (const int*)d_in[2];
  const float* evl  = (const float*)d_in[3];
  const float* W1   = (const float*)d_in[4];
  const float* b1   = (const float*)d_in[5];
  const float* W2   = (const float*)d_in[6];
  const float* b2   = (const float*)d_in[7];

  char* ws = (char*)d_ws;
  int2*   st   = (int2*)  (ws);               // 12.8 MB staging (dead before mlp)
  half_t* Pa   = (half_t*)(ws);               // 6.4 MB (aliases st lower half)
  half_t* Pb   = (half_t*)(ws + 6400000);     // 6.4 MB (aliases st upper half)
  int2*   ep   = (int2*)  (ws + 12800000);    // 12.8 MB
  int*    gcnt = (int*)   (ws + 25600000);    // 391 ints
  int*    bcur = (int*)   (ws + 25601600);    // 391 ints
  int*    goff = (int*)   (ws + 25603200);    // 392 ints
  int*    rp   = (int*)   (ws + 25604800);    // 50001 ints

  hipMemsetAsync(gcnt, 0, 3200, stream);  // gcnt + bcur

  bucket_count<<<196, 256, 0, stream>>>(edst, gcnt);
  bucket_scan<<<1, 512, 0, stream>>>(gcnt, goff);
  bin_edges<<<224, 256, 0, stream>>>(esrc, edst, evl, goff, bcur, st);
  build_csr<<<NBUCK, 256, 0, stream>>>(goff, st, rp, ep);

  mlp_kernel<<<782, 512, 0, stream>>>(x, W1, b1, W2, b2, Pa);

  spmm_kernel<0><<<12500, 256, 0, stream>>>(rp, ep, Pa, Pb);
  spmm_kernel<0><<<12500, 256, 0, stream>>>(rp, ep, Pb, Pa);
  spmm_kernel<0><<<12500, 256, 0, stream>>>(rp, ep, Pa, Pb);
  spmm_kernel<1><<<12500, 256, 0, stream>>>(rp, ep, Pb, d_out);
}